// Round 1
// baseline (499.987 us; speedup 1.0000x reference)
//
#include <hip/hip_runtime.h>
#include <math.h>

#define LOG2M 13
#define MHALF 8192            // complex FFT size (real length 16384)
#define NFREQ 8193

// tw[j] = exp(-2*pi*i*j/16384), j = 0..8191  (serves FFT stage twiddles AND rfft unpack)
static __global__ void twiddle_kernel(float2* __restrict__ tw) {
    int j = blockIdx.x * 256 + threadIdx.x;
    if (j < MHALF) {
        double th = (double)j * (3.14159265358979323846 / 8192.0); // 2*pi*j/16384
        tw[j] = make_float2((float)cos(th), (float)(-sin(th)));
    }
}

__launch_bounds__(256)
static __global__ void chisq_kernel(const float* __restrict__ tmpl,
                                    const float* __restrict__ strn,
                                    const float2* __restrict__ tw,
                                    float* __restrict__ out)
{
    __shared__ float2 Z[MHALF];                 // 64 KiB, reused for every phase
    float* F = reinterpret_cast<float*>(Z);     // 16384 floats
    int*   I = reinterpret_cast<int*>(Z);

    const int t   = threadIdx.x;
    const int row = blockIdx.x;
    const float ALPHA = 1.1920928955078125e-7f; // 4*DF/fs^2 = 2^-23 exactly

    float hre[32], him[32], sre[32], sim[32];
    float h_nyq, s_nyq;

    // ---------- in-place radix-2 DIF complex FFT of 8192 in LDS ----------
    // natural-order input (coalesced load, conflict-free LDS store);
    // output in bit-reversed index order.
    auto run_fft = [&](const float* src) {
        const float2* x = reinterpret_cast<const float2*>(src);
        #pragma unroll
        for (int i = 0; i < 32; i++) {
            int n = t + 256 * i;
            Z[n] = x[n];
        }
        __syncthreads();
        for (int s = LOG2M; s >= 1; s--) {
            const int half  = 1 << (s - 1);
            const int shift = 14 - s;           // tw16 index stride for w_m^j, m = 2^s
            #pragma unroll
            for (int it = 0; it < 16; it++) {
                int idx = t + 256 * it;          // butterfly id, 0..4095
                int j   = idx & (half - 1);
                int p1  = ((idx >> (s - 1)) << s) + j;
                int p2  = p1 + half;
                float2 u = Z[p1];
                float2 v = Z[p2];
                float2 w = tw[j << shift];
                float sr = u.x + v.x, si = u.y + v.y;
                float dr = u.x - v.x, di = u.y - v.y;
                Z[p1] = make_float2(sr, si);
                Z[p2] = make_float2(w.x * dr - w.y * di, w.x * di + w.y * dr);
            }
            __syncthreads();
        }
    };

    // ---------- rfft unpack: X[k] from Z (bit-reversed layout), k = 32t..32t+31 ----------
    auto extract = [&](float* re, float* im, float& nyq) {
        #pragma unroll
        for (int i = 0; i < 32; i++) {
            int k  = 32 * t + i;
            int ka = __brev((unsigned)k) >> (32 - LOG2M);
            int km = (MHALF - k) & (MHALF - 1);
            int kb = __brev((unsigned)km) >> (32 - LOG2M);
            float2 A  = Z[ka];
            float2 Bc = Z[kb];
            float Br = Bc.x, Bi = -Bc.y;            // conj(Z[M-k])
            float Er = 0.5f * (A.x + Br), Ei = 0.5f * (A.y + Bi);
            float Dr = 0.5f * (A.x - Br), Di = 0.5f * (A.y - Bi);
            float2 w = tw[k];                        // exp(-2*pi*i*k/16384)
            re[i] = Er + w.x * Di + w.y * Dr;
            im[i] = Ei + w.y * Di - w.x * Dr;
        }
        float2 z0 = Z[0];
        nyq = z0.x - z0.y;                           // X[8192] (real)
    };

    const float* srow = strn + (size_t)row * 16384;
    const float* hrow = tmpl + (size_t)row * 16384;

    run_fft(srow);
    extract(sre, sim, s_nyq);
    __syncthreads();                // all extraction reads done before overwrite

    run_fft(hrow);
    extract(hre, him, h_nyq);
    __syncthreads();                // LDS free for cum_h

    // ---------- cum_h (scaled by ALPHA), block scan ----------
    float run = 0.f;
    #pragma unroll
    for (int i = 0; i < 32; i++) run += ALPHA * (hre[i] * hre[i] + him[i] * him[i]);

    const int SCAN = 12288;         // 256 floats scan scratch (disjoint from cum region)
    F[SCAN + t] = run;
    __syncthreads();
    for (int off = 1; off < 256; off <<= 1) {
        float v = (t >= off) ? F[SCAN + t - off] : 0.f;
        __syncthreads();
        F[SCAN + t] += v;
        __syncthreads();
    }
    float base = F[SCAN + t] - run;

    // cum_h stored swizzled: phys(k) = k + (k>>5)  (conflict-free writes; max 8448)
    float c = base;
    #pragma unroll
    for (int i = 0; i < 32; i++) {
        c += ALPHA * (hre[i] * hre[i] + him[i] * him[i]);
        int k = 32 * t + i;
        F[k + (k >> 5)] = c;
    }
    if (t == 255) F[8192 + 256] = c + ALPHA * h_nyq * h_nyq;   // cum_h[8192]

    const int EDG  = 12800;         // 17 ints
    const int BINS = 13056;         // 16 floats
    const int TOT  = 13073;
    __syncthreads();

    float total_h = F[8192 + 256];
    if (t < 17) {
        // searchsorted(cum_h, (t/16)*total_h, side='right'), clipped to 8192
        float target = (float)t * 0.0625f * total_h;
        int lo = 0, hi = NFREQ;
        while (lo < hi) {
            int mid = (lo + hi) >> 1;
            float v = F[mid + (mid >> 5)];
            if (v <= target) lo = mid + 1; else hi = mid;
        }
        I[EDG + t] = lo < 8192 ? lo : 8192;
    }
    if (t >= 64 && t < 80) F[BINS + (t - 64)] = 0.f;
    if (t == 80) F[TOT] = 0.f;
    __syncthreads();

    int e[17];
    #pragma unroll
    for (int i = 0; i < 17; i++) e[i] = I[EDG + i];

    float invs = 1.0f / sqrtf(total_h);
    float qs   = ALPHA * invs;      // r[k] = qs * Re(conj(H[k]) * S[k])

    // ---------- segmented bin sums + total ----------
    float tot = 0.f;
    float acc = 0.f;
    int   cur = -1;
    #pragma unroll
    for (int i = 0; i < 32; i++) {
        int   k = 32 * t + i;
        float r = qs * (hre[i] * sre[i] + him[i] * sim[i]);
        tot += r;
        int b = -1;                  // k in bin b iff e[b] < k <= e[b+1]
        #pragma unroll
        for (int j = 0; j < 17; j++) b += (e[j] < k) ? 1 : 0;
        if (b != cur) {
            if (cur >= 0) atomicAdd(&F[BINS + cur], acc);
            acc = 0.f;
            cur = b;
        }
        acc += r;
    }
    if (cur >= 0) atomicAdd(&F[BINS + cur], acc);

    #pragma unroll
    for (int off = 32; off > 0; off >>= 1) tot += __shfl_down(tot, off);
    if ((t & 63) == 0) atomicAdd(&F[TOT], tot);

    if (t == 0) {                    // Nyquist bin (k = 8192)
        float rn = qs * (h_nyq * s_nyq);
        atomicAdd(&F[TOT], rn);
        int b = -1;
        #pragma unroll
        for (int j = 0; j < 17; j++) b += (e[j] < 8192) ? 1 : 0;
        if (b >= 0) atomicAdd(&F[BINS + b], rn);
    }
    __syncthreads();

    if (t == 0) {
        float total = F[TOT];
        float mean  = total * 0.0625f;
        float chisq = 0.f;
        #pragma unroll
        for (int j = 0; j < 16; j++) {
            float d = F[BINS + j] - mean;
            chisq += d * d;
        }
        out[row] = chisq * (16.0f / 15.0f);
    }
}

extern "C" void kernel_launch(void* const* d_in, const int* in_sizes, int n_in,
                              void* d_out, int out_size, void* d_ws, size_t ws_size,
                              hipStream_t stream) {
    const float* tmpl = (const float*)d_in[0];
    const float* strn = (const float*)d_in[1];
    float* outp = (float*)d_out;
    float2* tw  = (float2*)d_ws;                 // 64 KiB twiddle table

    int rows = in_sizes[0] / 16384;              // 1024

    hipLaunchKernelGGL(twiddle_kernel, dim3(32), dim3(256), 0, stream, tw);
    hipLaunchKernelGGL(chisq_kernel, dim3(rows), dim3(256), 0, stream,
                       tmpl, strn, tw, outp);
}

// Round 2
// 161.238 us; speedup vs baseline: 3.1009x; 3.1009x over previous
//
#include <hip/hip_runtime.h>
#include <math.h>

#define DPI 3.14159265358979323846

__device__ __forceinline__ float2 cmul(float2 a, float2 b) {
    return make_float2(a.x*b.x - a.y*b.y, a.x*b.y + a.y*b.x);
}
__device__ __forceinline__ float2 cadd(float2 a, float2 b){ return make_float2(a.x+b.x, a.y+b.y); }
__device__ __forceinline__ float2 csub(float2 a, float2 b){ return make_float2(a.x-b.x, a.y-b.y); }
__device__ __forceinline__ float2 mulnj(float2 a){ return make_float2(a.y, -a.x); } // * (0,-1)

// W_32^m = (cos, -sin)(2*pi*m/32)
__device__ const float TW32R[16] = {
    1.0f, 0.98078528040323045f, 0.92387953251128676f, 0.83146961230254524f,
    0.70710678118654752f, 0.55557023301960222f, 0.38268343236508977f, 0.19509032201612827f,
    0.0f, -0.19509032201612827f, -0.38268343236508977f, -0.55557023301960222f,
    -0.70710678118654752f, -0.83146961230254524f, -0.92387953251128676f, -0.98078528040323045f };
__device__ const float TW32I[16] = {
    0.0f, -0.19509032201612827f, -0.38268343236508977f, -0.55557023301960222f,
    -0.70710678118654752f, -0.83146961230254524f, -0.92387953251128676f, -0.98078528040323045f,
    -1.0f, -0.98078528040323045f, -0.92387953251128676f, -0.83146961230254524f,
    -0.70710678118654752f, -0.55557023301960222f, -0.38268343236508977f, -0.19509032201612827f };

__device__ const int BR5[32] = {0,16,8,24,4,20,12,28,2,18,10,26,6,22,14,30,
                                1,17,9,25,5,21,13,29,3,19,11,27,7,23,15,31};
__device__ const int BR3[8]  = {0,4,2,6,1,5,3,7};

template<int H>
__device__ __forceinline__ void stage32(float2* y) {
    #pragma unroll
    for (int g = 0; g < 32; g += 2*H) {
        #pragma unroll
        for (int j = 0; j < H; j++) {
            float2 u = y[g+j], v = y[g+j+H];
            y[g+j] = cadd(u, v);
            float2 d = csub(u, v);
            const int m = j * (16 / H);
            y[g+j+H] = (j == 0) ? d : cmul(d, make_float2(TW32R[m], TW32I[m]));
        }
    }
}
__device__ __forceinline__ void fft32(float2* y) {
    stage32<16>(y); stage32<8>(y); stage32<4>(y); stage32<2>(y); stage32<1>(y);
}

__device__ __forceinline__ void fft8(float2* v) {
    const float R2 = 0.70710678118654752f;
    float2 a0=cadd(v[0],v[4]), d0=csub(v[0],v[4]);
    float2 a1=cadd(v[1],v[5]), d1=csub(v[1],v[5]);
    float2 a2=cadd(v[2],v[6]), d2=csub(v[2],v[6]);
    float2 a3=cadd(v[3],v[7]), d3=csub(v[3],v[7]);
    float2 t1 = make_float2(R2*(d1.x+d1.y), R2*(d1.y-d1.x));   // * W8^1
    float2 t2 = mulnj(d2);                                      // * W8^2
    float2 t3 = make_float2(R2*(d3.y-d3.x), -R2*(d3.x+d3.y));   // * W8^3
    float2 b0=cadd(a0,a2), e0=csub(a0,a2);
    float2 b1=cadd(a1,a3), e1=mulnj(csub(a1,a3));
    float2 c0=cadd(d0,t2), f0=csub(d0,t2);
    float2 c1=cadd(t1,t3), f1=mulnj(csub(t1,t3));
    v[0]=cadd(b0,b1); v[1]=csub(b0,b1);
    v[2]=cadd(e0,e1); v[3]=csub(e0,e1);
    v[4]=cadd(c0,c1); v[5]=csub(c0,c1);
    v[6]=cadd(f0,f1); v[7]=csub(f0,f1);
}

// binary-decomposition powers: wp[m] = w^m, m=0..15, mult depth <= 3
__device__ __forceinline__ void pow16(float2 w, float2* wp) {
    wp[0] = make_float2(1.f, 0.f);
    wp[1] = w;
    wp[2] = cmul(w, w);
    wp[3] = cmul(wp[2], w);
    wp[4] = cmul(wp[2], wp[2]);
    wp[5] = cmul(wp[4], wp[1]);
    wp[6] = cmul(wp[4], wp[2]);
    wp[7] = cmul(wp[4], wp[3]);
    wp[8] = cmul(wp[4], wp[4]);
    wp[9] = cmul(wp[8], wp[1]);
    wp[10] = cmul(wp[8], wp[2]);
    wp[11] = cmul(wp[8], wp[3]);
    wp[12] = cmul(wp[8], wp[4]);
    wp[13] = cmul(wp[8], wp[5]);
    wp[14] = cmul(wp[8], wp[6]);
    wp[15] = cmul(wp[8], wp[7]);
}

// ws layout (float2): [0,256) W_8192^t | [256,512) W_512^t | [512,544) W_16384^i | [544,552) W_256^b
static __global__ void init_tw(float2* __restrict__ ws) {
    int t = threadIdx.x;
    ws[t]       = make_float2((float)cos(DPI*t/4096.0), (float)(-sin(DPI*t/4096.0)));
    ws[256 + t] = make_float2((float)cos(DPI*t/256.0),  (float)(-sin(DPI*t/256.0)));
    if (t < 32) ws[512 + t] = make_float2((float)cos(DPI*t/8192.0), (float)(-sin(DPI*t/8192.0)));
    if (t < 8)  ws[544 + t] = make_float2((float)cos(DPI*t/128.0),  (float)(-sin(DPI*t/128.0)));
}

__launch_bounds__(256, 2)
static __global__ void chisq_kernel(const float* __restrict__ tmpl,
                                    const float* __restrict__ strn,
                                    const float2* __restrict__ ws,
                                    float* __restrict__ out)
{
    __shared__ float2 Z[8192];                  // 64 KiB, reused every phase
    float* F = reinterpret_cast<float*>(Z);
    int*   I = reinterpret_cast<int*>(Z);

    const int t   = threadIdx.x;
    const int row = blockIdx.x;
    const float ALPHA = 1.1920928955078125e-7f; // 4*DF/fs^2 = 2^-23

    const float2* twT  = ws;
    const float2* twC  = ws + 256;
    const float2* twI  = ws + 512;
    const float2* twB8 = ws + 544;

    const int k1 = t & 31;
    const int bb = t >> 5;

    float sre[32], sim[32];                     // S spectrum, later |H|^2 / Re(conj H * S)
    float s_nyq, h_nyq;

    // -------- four-step FFT of 8192 complex: 32(reg) x 32(reg) x 8(reg), 2 LDS transposes --------
    auto do_fft = [&](const float* src) {
        const float2* x = reinterpret_cast<const float2*>(src);
        float2 y[32];
        #pragma unroll
        for (int n1 = 0; n1 < 32; n1++) y[n1] = x[n1*256 + t];
        fft32(y);                                // y[p] = Y[BR5[p]]
        float2 wp[16]; pow16(twT[t], wp);        // W_8192^t powers
        float2 w16 = cmul(wp[8], wp[8]);
        __syncthreads();                         // previous phase's LDS reads complete
        #pragma unroll
        for (int p = 0; p < 32; p++) {           // T1 write: logical [n2=t][kk], XOR-swizzled
            int kk = BR5[p];
            float2 val = y[p];
            if (kk > 0) val = (kk < 16) ? cmul(val, wp[kk]) : cmul(val, cmul(wp[kk-16], w16));
            Z[(t << 5) | (kk ^ (t & 31))] = val;
        }
        __syncthreads();
        #pragma unroll
        for (int a = 0; a < 32; a++) {           // T1 read: (k1, b) gathers n2 = 8a+b
            int n2 = 8*a + bb;
            y[a] = Z[(n2 << 5) | (k1 ^ (n2 & 31))];
        }
        fft32(y);
        float2 wq[16]; pow16(twB8[bb], wq);      // W_256^b powers
        float2 wq16 = cmul(wq[8], wq[8]);
        __syncthreads();                         // all T1 reads done
        #pragma unroll
        for (int p = 0; p < 32; p++) {           // T2 write: logical row r = 8c+b, col k1
            int cc = BR5[p];
            float2 val = y[p];
            if (cc > 0) val = (cc < 16) ? cmul(val, wq[cc]) : cmul(val, cmul(wq[cc-16], wq16));
            int r = 8*cc + bb;
            Z[(r << 5) | (k1 ^ (r & 31))] = val;
        }
        __syncthreads();
        #pragma unroll
        for (int p = 0; p < 4; p++) {            // T2 read: (k1, c=4*cg+p), b2=0..7
            #pragma unroll
            for (int b2 = 0; b2 < 8; b2++) {
                int r = 8*(4*bb + p) + b2;
                y[p*8 + b2] = Z[(r << 5) | (k1 ^ (r & 31))];
            }
        }
        __syncthreads();                         // all T2 reads done
        #pragma unroll
        for (int p = 0; p < 4; p++) {
            int c = 4*bb + p;
            float2 v8[8];
            #pragma unroll
            for (int b2 = 0; b2 < 8; b2++) v8[b2] = y[p*8 + b2];
            fft8(v8);                            // v8[s] = out[BR3[s]]
            #pragma unroll
            for (int s = 0; s < 8; s++) {
                int d = BR3[s];
                Z[32*c + 1024*d + (k1 ^ c)] = v8[s];   // k = k1+32c+1024d, swizzled low5
            }
        }
        __syncthreads();                         // spectrum (natural order, swizzled) ready
    };

    const float* srow = strn + (size_t)row * 16384;
    const float* hrow = tmpl + (size_t)row * 16384;

    // ---- strain ----
    do_fft(srow);
    {
        float2 cv = twC[t];
        #pragma unroll
        for (int i = 0; i < 32; i++) {
            int k = (t << 5) + i;
            float2 A  = Z[(t << 5) + (i ^ (t & 31))];
            int m = (8192 - k) & 8191;
            float2 Bc = Z[(m & ~31) | ((m & 31) ^ ((m >> 5) & 31))];
            float2 w = cmul(cv, twI[i]);
            float Er = 0.5f*(A.x + Bc.x), Ei = 0.5f*(A.y - Bc.y);
            float Dr = 0.5f*(A.x - Bc.x), Di = 0.5f*(A.y + Bc.y);
            sre[i] = Er + w.x*Di + w.y*Dr;
            sim[i] = Ei + w.y*Di - w.x*Dr;
        }
        float2 z0 = Z[0];
        s_nyq = z0.x - z0.y;
    }

    // ---- template (pre-T1 sync inside do_fft protects the reads above) ----
    do_fft(hrow);
    {
        float2 cv = twC[t];
        #pragma unroll
        for (int i = 0; i < 32; i++) {
            int k = (t << 5) + i;
            float2 A  = Z[(t << 5) + (i ^ (t & 31))];
            int m = (8192 - k) & 8191;
            float2 Bc = Z[(m & ~31) | ((m & 31) ^ ((m >> 5) & 31))];
            float2 w = cmul(cv, twI[i]);
            float Er = 0.5f*(A.x + Bc.x), Ei = 0.5f*(A.y - Bc.y);
            float Dr = 0.5f*(A.x - Bc.x), Di = 0.5f*(A.y + Bc.y);
            float hr = Er + w.x*Di + w.y*Dr;
            float hi = Ei + w.y*Di - w.x*Dr;
            float pr = hr*sre[i] + hi*sim[i];
            sre[i] = hr*hr + hi*hi;              // |H|^2
            sim[i] = pr;                         // Re(conj(H) * S)
        }
        float2 z0 = Z[0];
        h_nyq = z0.x - z0.y;
    }
    __syncthreads();                             // spectrum reads done; LDS free

    // ---- cum_h: wave-shuffle scan (1 sync) ----
    float run = 0.f;
    #pragma unroll
    for (int i = 0; i < 32; i++) run += ALPHA * sre[i];

    const int lane = t & 63, wid = t >> 6;
    float v = run;
    #pragma unroll
    for (int off = 1; off < 64; off <<= 1) {
        float o = __shfl_up(v, off, 64);
        if (lane >= off) v += o;
    }
    const int SCANW = 12288;
    if (lane == 63) F[SCANW + wid] = v;
    __syncthreads();
    float wbase = 0.f;
    #pragma unroll
    for (int w2 = 0; w2 < 3; w2++) if (w2 < wid) wbase += F[SCANW + w2];
    float base = wbase + v - run;                // exclusive prefix

    float cum = base;
    #pragma unroll
    for (int i = 0; i < 32; i++) {               // cum stored at phys(k)=k+(k>>5): conflict-free
        cum += ALPHA * sre[i];
        int k = 32*t + i;
        F[k + (k >> 5)] = cum;
    }
    if (t == 255) F[8448] = cum + ALPHA * h_nyq * h_nyq;   // cum_h[8192]
    __syncthreads();

    // ---- edges + bin init ----
    const int EDG  = 12800;                      // 17 ints
    const int BINS = 13056;                      // 16 floats
    const int TOT  = 13073;
    float total_h = F[8448];
    if (t < 17) {
        float target = (float)t * 0.0625f * total_h;
        int lo = 0, hi = 8193;
        while (lo < hi) {
            int mid = (lo + hi) >> 1;
            float vv = F[mid + (mid >> 5)];
            if (vv <= target) lo = mid + 1; else hi = mid;
        }
        I[EDG + t] = lo < 8192 ? lo : 8192;
    }
    if (t >= 64 && t < 80) F[BINS + (t - 64)] = 0.f;
    if (t == 80) F[TOT] = 0.f;
    __syncthreads();

    int e[17];
    #pragma unroll
    for (int i = 0; i < 17; i++) e[i] = I[EDG + i];

    float invs = 1.0f / sqrtf(total_h);
    float qs   = ALPHA * invs;

    // ---- segmented bin sums + total ----
    float tot = 0.f, acc = 0.f;
    int   cur = -1;
    #pragma unroll
    for (int i = 0; i < 32; i++) {
        int   k = 32*t + i;
        float r = qs * sim[i];
        tot += r;
        int bn = -1;                             // k in bin bn iff e[bn] < k <= e[bn+1]
        #pragma unroll
        for (int j = 0; j < 17; j++) bn += (e[j] < k) ? 1 : 0;
        if (bn != cur) {
            if (cur >= 0) atomicAdd(&F[BINS + cur], acc);
            acc = 0.f;
            cur = bn;
        }
        acc += r;
    }
    if (cur >= 0) atomicAdd(&F[BINS + cur], acc);

    #pragma unroll
    for (int off = 32; off > 0; off >>= 1) tot += __shfl_down(tot, off);
    if ((t & 63) == 0) atomicAdd(&F[TOT], tot);

    if (t == 0) {                                // Nyquist term (k = 8192)
        float rn = qs * (h_nyq * s_nyq);
        atomicAdd(&F[TOT], rn);
        int bn = -1;
        #pragma unroll
        for (int j = 0; j < 17; j++) bn += (e[j] < 8192) ? 1 : 0;
        if (bn >= 0) atomicAdd(&F[BINS + bn], rn);
    }
    __syncthreads();

    if (t == 0) {
        float total = F[TOT];
        float mean  = total * 0.0625f;
        float chisq = 0.f;
        #pragma unroll
        for (int j = 0; j < 16; j++) {
            float d = F[BINS + j] - mean;
            chisq += d * d;
        }
        out[row] = chisq * (16.0f / 15.0f);
    }
}

extern "C" void kernel_launch(void* const* d_in, const int* in_sizes, int n_in,
                              void* d_out, int out_size, void* d_ws, size_t ws_size,
                              hipStream_t stream) {
    const float* tmpl = (const float*)d_in[0];
    const float* strn = (const float*)d_in[1];
    float* outp = (float*)d_out;
    float2* ws  = (float2*)d_ws;                 // ~4.4 KiB twiddle tables

    int rows = in_sizes[0] / 16384;              // 1024

    hipLaunchKernelGGL(init_tw, dim3(1), dim3(256), 0, stream, ws);
    hipLaunchKernelGGL(chisq_kernel, dim3(rows), dim3(256), 0, stream,
                       tmpl, strn, ws, outp);
}

// Round 3
// 86.024 us; speedup vs baseline: 5.8122x; 1.8743x over previous
//
#include <hip/hip_runtime.h>
#include <math.h>

#define DPI 3.14159265358979323846

__device__ __forceinline__ float2 cmul(float2 a, float2 b) {
    return make_float2(a.x*b.x - a.y*b.y, a.x*b.y + a.y*b.x);
}
__device__ __forceinline__ float2 cadd(float2 a, float2 b){ return make_float2(a.x+b.x, a.y+b.y); }
__device__ __forceinline__ float2 csub(float2 a, float2 b){ return make_float2(a.x-b.x, a.y-b.y); }
__device__ __forceinline__ float2 mulnj(float2 a){ return make_float2(a.y, -a.x); } // * (0,-1)

// W_32^m = (cos, -sin)(2*pi*m/32)
__device__ const float TW32R[16] = {
    1.0f, 0.98078528040323045f, 0.92387953251128676f, 0.83146961230254524f,
    0.70710678118654752f, 0.55557023301960222f, 0.38268343236508977f, 0.19509032201612827f,
    0.0f, -0.19509032201612827f, -0.38268343236508977f, -0.55557023301960222f,
    -0.70710678118654752f, -0.83146961230254524f, -0.92387953251128676f, -0.98078528040323045f };
__device__ const float TW32I[16] = {
    0.0f, -0.19509032201612827f, -0.38268343236508977f, -0.55557023301960222f,
    -0.70710678118654752f, -0.83146961230254524f, -0.92387953251128676f, -0.98078528040323045f,
    -1.0f, -0.98078528040323045f, -0.92387953251128676f, -0.83146961230254524f,
    -0.70710678118654752f, -0.55557023301960222f, -0.38268343236508977f, -0.19509032201612827f };

__device__ const int BR5[32] = {0,16,8,24,4,20,12,28,2,18,10,26,6,22,14,30,
                                1,17,9,25,5,21,13,29,3,19,11,27,7,23,15,31};
__device__ const int BR3[8]  = {0,4,2,6,1,5,3,7};

template<int H>
__device__ __forceinline__ void stage32(float2* y) {
    #pragma unroll
    for (int g = 0; g < 32; g += 2*H) {
        #pragma unroll
        for (int j = 0; j < H; j++) {
            float2 u = y[g+j], v = y[g+j+H];
            y[g+j] = cadd(u, v);
            float2 d = csub(u, v);
            const int m = j * (16 / H);
            y[g+j+H] = (j == 0) ? d : cmul(d, make_float2(TW32R[m], TW32I[m]));
        }
    }
}
__device__ __forceinline__ void fft32(float2* y) {
    stage32<16>(y); stage32<8>(y); stage32<4>(y); stage32<2>(y); stage32<1>(y);
}

__device__ __forceinline__ void fft8(float2* v) {
    const float R2 = 0.70710678118654752f;
    float2 a0=cadd(v[0],v[4]), d0=csub(v[0],v[4]);
    float2 a1=cadd(v[1],v[5]), d1=csub(v[1],v[5]);
    float2 a2=cadd(v[2],v[6]), d2=csub(v[2],v[6]);
    float2 a3=cadd(v[3],v[7]), d3=csub(v[3],v[7]);
    float2 t1 = make_float2(R2*(d1.x+d1.y), R2*(d1.y-d1.x));   // * W8^1
    float2 t2 = mulnj(d2);                                      // * W8^2
    float2 t3 = make_float2(R2*(d3.y-d3.x), -R2*(d3.x+d3.y));   // * W8^3
    float2 b0=cadd(a0,a2), e0=csub(a0,a2);
    float2 b1=cadd(a1,a3), e1=mulnj(csub(a1,a3));
    float2 c0=cadd(d0,t2), f0=csub(d0,t2);
    float2 c1=cadd(t1,t3), f1=mulnj(csub(t1,t3));
    v[0]=cadd(b0,b1); v[1]=csub(b0,b1);
    v[2]=cadd(e0,e1); v[3]=csub(e0,e1);
    v[4]=cadd(c0,c1); v[5]=csub(c0,c1);
    v[6]=cadd(f0,f1); v[7]=csub(f0,f1);
}

// wp[m] = w^m, m=0..15, mult depth <= 3
__device__ __forceinline__ void pow16(float2 w, float2* wp) {
    wp[0] = make_float2(1.f, 0.f);
    wp[1] = w;
    wp[2] = cmul(w, w);
    wp[3] = cmul(wp[2], w);
    wp[4] = cmul(wp[2], wp[2]);
    wp[5] = cmul(wp[4], wp[1]);
    wp[6] = cmul(wp[4], wp[2]);
    wp[7] = cmul(wp[4], wp[3]);
    wp[8] = cmul(wp[4], wp[4]);
    wp[9] = cmul(wp[8], wp[1]);
    wp[10] = cmul(wp[8], wp[2]);
    wp[11] = cmul(wp[8], wp[3]);
    wp[12] = cmul(wp[8], wp[4]);
    wp[13] = cmul(wp[8], wp[5]);
    wp[14] = cmul(wp[8], wp[6]);
    wp[15] = cmul(wp[8], wp[7]);
}

// ws layout (float2): [0,256) W_8192^t | [256,768) W_1024^t (t<512) |
//                     [768,784) W_16384^i | [784,792) W_256^b
static __global__ void init_tw(float2* __restrict__ ws) {
    int t = threadIdx.x;                         // 512 threads
    if (t < 256) ws[t] = make_float2((float)cos(DPI*t/4096.0), (float)(-sin(DPI*t/4096.0)));
    ws[256 + t] = make_float2((float)cos(DPI*t/512.0), (float)(-sin(DPI*t/512.0)));
    if (t < 16) ws[768 + t] = make_float2((float)cos(DPI*t/8192.0), (float)(-sin(DPI*t/8192.0)));
    if (t < 8)  ws[784 + t] = make_float2((float)cos(DPI*t/128.0),  (float)(-sin(DPI*t/128.0)));
}

__launch_bounds__(512, 2)
static __global__ void chisq_kernel(const float* __restrict__ tmpl,
                                    const float* __restrict__ strn,
                                    const float2* __restrict__ ws,
                                    float* __restrict__ out)
{
    __shared__ float2 Z[16384];                 // 128 KiB: [0,8192)=strain, [8192,16384)=template
    float* F = reinterpret_cast<float*>(Z);
    int*   I = reinterpret_cast<int*>(Z);

    const int t    = threadIdx.x;               // 0..511
    const int half = t >> 8;                    // 0 = strain, 1 = template
    const int tt   = t & 255;
    const int k1   = tt & 31;
    const int bb   = tt >> 5;
    const int row  = blockIdx.x;
    const float ALPHA = 1.1920928955078125e-7f; // 4*DF/fs^2 = 2^-23

    const float2* twT  = ws;
    const float2* twC  = ws + 256;
    const float2* twI  = ws + 768;
    const float2* twB8 = ws + 784;

    float2* Zh = Z + (half << 13);
    const float* src = (half ? tmpl : strn) + (size_t)row * 16384;

    // -------- four-step FFT of 8192 complex (even/odd-packed real row), both halves in parallel --------
    {
        const float2* x = reinterpret_cast<const float2*>(src);
        float2 y[32];
        #pragma unroll
        for (int n1 = 0; n1 < 32; n1++) y[n1] = x[n1*256 + tt];
        fft32(y);                                // y[p] = Y[BR5[p]]
        float2 wp[16]; pow16(twT[tt], wp);       // W_8192^tt powers
        float2 w16 = cmul(wp[8], wp[8]);
        #pragma unroll
        for (int p = 0; p < 32; p++) {           // T1 write: [n2=tt][kk], XOR-swizzled
            int kk = BR5[p];
            float2 val = y[p];
            if (kk > 0) val = (kk < 16) ? cmul(val, wp[kk]) : cmul(val, cmul(wp[kk-16], w16));
            Zh[(tt << 5) | (kk ^ (tt & 31))] = val;
        }
        __syncthreads();
        #pragma unroll
        for (int a = 0; a < 32; a++) {           // T1 read: (k1, bb) gathers n2 = 8a+bb
            int n2 = 8*a + bb;
            y[a] = Zh[(n2 << 5) | (k1 ^ (n2 & 31))];
        }
        fft32(y);
        float2 wq[16]; pow16(twB8[bb], wq);      // W_256^bb powers
        float2 wq16 = cmul(wq[8], wq[8]);
        __syncthreads();                         // all T1 reads done
        #pragma unroll
        for (int p = 0; p < 32; p++) {           // T2 write: row r = 8c+bb, col k1
            int cc = BR5[p];
            float2 val = y[p];
            if (cc > 0) val = (cc < 16) ? cmul(val, wq[cc]) : cmul(val, cmul(wq[cc-16], wq16));
            int r = 8*cc + bb;
            Zh[(r << 5) | (k1 ^ (r & 31))] = val;
        }
        __syncthreads();
        #pragma unroll
        for (int p = 0; p < 4; p++) {            // T2 read
            #pragma unroll
            for (int b2 = 0; b2 < 8; b2++) {
                int r = 8*(4*bb + p) + b2;
                y[p*8 + b2] = Zh[(r << 5) | (k1 ^ (r & 31))];
            }
        }
        __syncthreads();                         // all T2 reads done
        #pragma unroll
        for (int p = 0; p < 4; p++) {
            int c = 4*bb + p;
            float2 v8[8];
            #pragma unroll
            for (int b2 = 0; b2 < 8; b2++) v8[b2] = y[p*8 + b2];
            fft8(v8);                            // v8[s] = out[BR3[s]]
            #pragma unroll
            for (int s = 0; s < 8; s++) {
                int d = BR3[s];
                Zh[32*c + 1024*d + (k1 ^ c)] = v8[s];   // k = k1+32c+1024d, swizzled low5
            }
        }
        __syncthreads();                         // both spectra ready (swizzled natural order)
    }

    // -------- rfft unpack of both spectra + pointwise products, 16 bins/thread --------
    float2* ZS = Z;
    float2* ZH = Z + 8192;
    float2 zs0 = ZS[0], zh0 = ZH[0];
    const float s_nyq = zs0.x - zs0.y;
    const float h_nyq = zh0.x - zh0.y;

    float hh[16], hs[16];                        // |H|^2, Re(conj(H)*S)
    {
        float2 cv = twC[t];
        #pragma unroll
        for (int i = 0; i < 16; i++) {
            int k = (t << 4) + i;
            int m = (8192 - k) & 8191;
            int ak = (k & ~31) | ((k & 31) ^ ((k >> 5) & 31));
            int am = (m & ~31) | ((m & 31) ^ ((m >> 5) & 31));
            float2 As = ZS[ak], Bs = ZS[am];
            float2 Ah = ZH[ak], Bh = ZH[am];
            float2 w = cmul(cv, twI[i]);         // W_16384^k
            float Er = 0.5f*(As.x + Bs.x), Ei = 0.5f*(As.y - Bs.y);
            float Dr = 0.5f*(As.x - Bs.x), Di = 0.5f*(As.y + Bs.y);
            float sr = Er + w.x*Di + w.y*Dr;
            float si = Ei + w.y*Di - w.x*Dr;
            Er = 0.5f*(Ah.x + Bh.x); Ei = 0.5f*(Ah.y - Bh.y);
            Dr = 0.5f*(Ah.x - Bh.x); Di = 0.5f*(Ah.y + Bh.y);
            float hr = Er + w.x*Di + w.y*Dr;
            float hi = Ei + w.y*Di - w.x*Dr;
            hh[i] = hr*hr + hi*hi;
            hs[i] = hr*sr + hi*si;
        }
    }
    __syncthreads();                             // all spectrum reads done; LDS free

    // -------- cum_h: wave shuffle scan over 8 waves --------
    const int SCANW = 16500;                     // 8 floats (upper LDS half, spectra dead)
    const int EDG   = 16520;                     // 17 ints
    const int BINS  = 16544;                     // 16 floats
    const int TOT   = 16561;

    float run = 0.f;
    #pragma unroll
    for (int i = 0; i < 16; i++) run += ALPHA * hh[i];

    const int lane = t & 63, wid = t >> 6;
    float v = run;
    #pragma unroll
    for (int off = 1; off < 64; off <<= 1) {
        float o = __shfl_up(v, off, 64);
        if (lane >= off) v += o;
    }
    if (lane == 63) F[SCANW + wid] = v;
    __syncthreads();
    float wbase = 0.f;
    #pragma unroll
    for (int w2 = 0; w2 < 7; w2++) if (w2 < wid) wbase += F[SCANW + w2];
    float base = wbase + v - run;                // exclusive prefix

    float cum = base;
    #pragma unroll
    for (int i = 0; i < 16; i++) {               // cum at phys(k)=k+(k>>5)
        cum += ALPHA * hh[i];
        int k = (t << 4) + i;
        F[k + (k >> 5)] = cum;
    }
    if (t == 511) F[8448] = cum + ALPHA * h_nyq * h_nyq;   // cum_h[8192]
    __syncthreads();

    // -------- edges (searchsorted right) + bin init --------
    float total_h = F[8448];
    if (t < 17) {
        float target = (float)t * 0.0625f * total_h;
        int lo = 0, hi = 8193;
        while (lo < hi) {
            int mid = (lo + hi) >> 1;
            float vv = F[mid + (mid >> 5)];
            if (vv <= target) lo = mid + 1; else hi = mid;
        }
        I[EDG + t] = lo < 8192 ? lo : 8192;
    }
    if (t >= 64 && t < 80) F[BINS + (t - 64)] = 0.f;
    if (t == 80) F[TOT] = 0.f;
    __syncthreads();

    int e[17];
    #pragma unroll
    for (int i = 0; i < 17; i++) e[i] = I[EDG + i];

    float invs = 1.0f / sqrtf(total_h);
    float qs   = ALPHA * invs;

    // -------- segmented bin sums + total --------
    float tot = 0.f, acc = 0.f;
    int   cur = -1;
    #pragma unroll
    for (int i = 0; i < 16; i++) {
        int   k = (t << 4) + i;
        float r = qs * hs[i];
        tot += r;
        int bn = -1;                             // k in bin bn iff e[bn] < k <= e[bn+1]
        #pragma unroll
        for (int j = 0; j < 17; j++) bn += (e[j] < k) ? 1 : 0;
        if (bn != cur) {
            if (cur >= 0) atomicAdd(&F[BINS + cur], acc);
            acc = 0.f;
            cur = bn;
        }
        acc += r;
    }
    if (cur >= 0) atomicAdd(&F[BINS + cur], acc);

    #pragma unroll
    for (int off = 32; off > 0; off >>= 1) tot += __shfl_down(tot, off);
    if ((t & 63) == 0) atomicAdd(&F[TOT], tot);

    if (t == 0) {                                // Nyquist term (k = 8192)
        float rn = qs * (h_nyq * s_nyq);
        atomicAdd(&F[TOT], rn);
        int bn = -1;
        #pragma unroll
        for (int j = 0; j < 17; j++) bn += (e[j] < 8192) ? 1 : 0;
        if (bn >= 0) atomicAdd(&F[BINS + bn], rn);
    }
    __syncthreads();

    if (t == 0) {
        float total = F[TOT];
        float mean  = total * 0.0625f;
        float chisq = 0.f;
        #pragma unroll
        for (int j = 0; j < 16; j++) {
            float d = F[BINS + j] - mean;
            chisq += d * d;
        }
        out[row] = chisq * (16.0f / 15.0f);
    }
}

extern "C" void kernel_launch(void* const* d_in, const int* in_sizes, int n_in,
                              void* d_out, int out_size, void* d_ws, size_t ws_size,
                              hipStream_t stream) {
    const float* tmpl = (const float*)d_in[0];
    const float* strn = (const float*)d_in[1];
    float* outp = (float*)d_out;
    float2* ws  = (float2*)d_ws;                 // ~6.2 KiB twiddle tables

    int rows = in_sizes[0] / 16384;              // 1024

    hipLaunchKernelGGL(init_tw, dim3(1), dim3(512), 0, stream, ws);
    hipLaunchKernelGGL(chisq_kernel, dim3(rows), dim3(512), 0, stream,
                       tmpl, strn, ws, outp);
}

// Round 4
// 82.562 us; speedup vs baseline: 6.0559x; 1.0419x over previous
//
#include <hip/hip_runtime.h>
#include <math.h>

#define DPI 3.14159265358979323846

__device__ __forceinline__ float2 cmul(float2 a, float2 b) {
    return make_float2(a.x*b.x - a.y*b.y, a.x*b.y + a.y*b.x);
}
__device__ __forceinline__ float2 cadd(float2 a, float2 b){ return make_float2(a.x+b.x, a.y+b.y); }
__device__ __forceinline__ float2 csub(float2 a, float2 b){ return make_float2(a.x-b.x, a.y-b.y); }

// W_32^m = (cos, -sin)(2*pi*m/32), m = 0..15
__device__ const float TW32R[16] = {
    1.0f, 0.98078528040323045f, 0.92387953251128676f, 0.83146961230254524f,
    0.70710678118654752f, 0.55557023301960222f, 0.38268343236508977f, 0.19509032201612827f,
    0.0f, -0.19509032201612827f, -0.38268343236508977f, -0.55557023301960222f,
    -0.70710678118654752f, -0.83146961230254524f, -0.92387953251128676f, -0.98078528040323045f };
__device__ const float TW32I[16] = {
    0.0f, -0.19509032201612827f, -0.38268343236508977f, -0.55557023301960222f,
    -0.70710678118654752f, -0.83146961230254524f, -0.92387953251128676f, -0.98078528040323045f,
    -1.0f, -0.98078528040323045f, -0.92387953251128676f, -0.83146961230254524f,
    -0.70710678118654752f, -0.55557023301960222f, -0.38268343236508977f, -0.19509032201612827f };

__device__ const int BR4[16] = {0,8,4,12,2,10,6,14,1,9,5,13,3,11,7,15};

// DIF stage for register FFT of size 16, butterfly half-span H.
// Twiddle exponent in W_32 units: m = j*(16/H) (valid for N=16 since TW32 is W_32).
template<int H>
__device__ __forceinline__ void stage16(float2* y) {
    #pragma unroll
    for (int g = 0; g < 16; g += 2*H) {
        #pragma unroll
        for (int j = 0; j < H; j++) {
            float2 u = y[g+j], v = y[g+j+H];
            y[g+j] = cadd(u, v);
            float2 d = csub(u, v);
            const int m = j * (16 / H);
            y[g+j+H] = (j == 0) ? d : cmul(d, make_float2(TW32R[m], TW32I[m]));
        }
    }
}
__device__ __forceinline__ void fft16(float2* y) {
    stage16<8>(y); stage16<4>(y); stage16<2>(y); stage16<1>(y);
}   // y[p] = OUT[BR4[p]]

// wp[m] = w^m, m=0..15, mult depth <= 3
__device__ __forceinline__ void pow16(float2 w, float2* wp) {
    wp[0] = make_float2(1.f, 0.f);
    wp[1] = w;
    wp[2] = cmul(w, w);
    wp[3] = cmul(wp[2], w);
    wp[4] = cmul(wp[2], wp[2]);
    wp[5] = cmul(wp[4], wp[1]);
    wp[6] = cmul(wp[4], wp[2]);
    wp[7] = cmul(wp[4], wp[3]);
    wp[8] = cmul(wp[4], wp[4]);
    wp[9] = cmul(wp[8], wp[1]);
    wp[10] = cmul(wp[8], wp[2]);
    wp[11] = cmul(wp[8], wp[3]);
    wp[12] = cmul(wp[8], wp[4]);
    wp[13] = cmul(wp[8], wp[5]);
    wp[14] = cmul(wp[8], wp[6]);
    wp[15] = cmul(wp[8], wp[7]);
}

// ws layout (float2): [0,512) W_8192^u | [512,544) W_512^j | [544,1568) W_2048^t | [1568,1576) W_16384^i
static __global__ void init_tw(float2* __restrict__ ws) {
    int g = blockIdx.x * 1024 + threadIdx.x;
    if (g < 512) {
        ws[g] = make_float2((float)cos(DPI*g/4096.0), (float)(-sin(DPI*g/4096.0)));
    } else if (g < 544) {
        int j = g - 512;
        ws[g] = make_float2((float)cos(DPI*j/256.0), (float)(-sin(DPI*j/256.0)));
    } else if (g < 1568) {
        int q = g - 544;
        ws[g] = make_float2((float)cos(DPI*q/1024.0), (float)(-sin(DPI*q/1024.0)));
    } else if (g < 1576) {
        int i = g - 1568;
        ws[g] = make_float2((float)cos(DPI*i/8192.0), (float)(-sin(DPI*i/8192.0)));
    }
}

__launch_bounds__(1024)
static __global__ void chisq_kernel(const float* __restrict__ tmpl,
                                    const float* __restrict__ strn,
                                    const float2* __restrict__ ws,
                                    float* __restrict__ out)
{
    __shared__ float2 Z[16384];                 // 128 KiB: [0,8192)=strain, [8192,16384)=template
    float* F = reinterpret_cast<float*>(Z);
    int*   I = reinterpret_cast<int*>(Z);

    const int t    = threadIdx.x;               // 0..1023
    const int half = t >> 9;                    // 0 = strain, 1 = template
    const int u    = t & 511;
    const int row  = blockIdx.x;
    const float ALPHA = 1.1920928955078125e-7f; // 4*DF/fs^2 = 2^-23

    const float2* tw8192 = ws;                  // W_8192^u, u<512
    const float2* tw512  = ws + 512;            // W_512^j,  j<32
    const float2* twC    = ws + 544;            // W_2048^t, t<1024
    const float2* twI    = ws + 1568;           // W_16384^i, i<8

    float2* Zh = Z + (half << 13);
    const float* src = (half ? tmpl : strn) + (size_t)row * 16384;

    // -------- FFT 8192 = 16 x 16 x (2 x 16), 512 threads/signal, 16 elems/thread --------
    {
        const float2* x = reinterpret_cast<const float2*>(src);
        float2 y[16];

        // ---- stage 1: fft16 over n1 (n = n1*512 + u), twiddle W_8192^{u*k1} ----
        #pragma unroll
        for (int n1 = 0; n1 < 16; n1++) y[n1] = x[n1*512 + u];
        fft16(y);
        {
            float2 wp[16]; pow16(tw8192[u], wp);
            #pragma unroll
            for (int p = 0; p < 16; p++) {
                int k1 = BR4[p];
                float2 val = y[p];
                if (k1 > 0) val = cmul(val, wp[k1]);
                Zh[(u << 4) | (k1 ^ (u & 15))] = val;   // L1[u][k1], swizzled
            }
        }
        __syncthreads();

        // ---- stage 2: fft16 over n2 (u = n2*32 + j), twiddle W_512^{j*k2} ----
        const int k1s = u >> 5, js = u & 31;
        #pragma unroll
        for (int n2 = 0; n2 < 16; n2++)
            y[n2] = Zh[((n2*32 + js) << 4) | (k1s ^ (js & 15))];
        __syncthreads();                          // all L1 reads done before L2 writes
        fft16(y);
        {
            float2 wq[16]; pow16(tw512[js], wq);
            #pragma unroll
            for (int p = 0; p < 16; p++) {
                int k2 = BR4[p];
                float2 val = y[p];
                if (k2 > 0) val = cmul(val, wq[k2]);
                Zh[(k1s << 9) + (k2 << 5) + (js ^ k2)] = val;  // L2[k1][k2][j], swizzled
            }
        }
        __syncthreads();

        // ---- stage 3: radix-2 (j2, j2+16) + fft16 over j2 ----
        // f=0: sum-half (s1=0); f=1: diff-half * W_32^{j2} (s1=1). f is wave-uniform.
        const int f = u >> 8, k1t = (u >> 4) & 15, k2t = u & 15;
        const int base = (k1t << 9) + (k2t << 5);
        float2 A[16], B[16];
        #pragma unroll
        for (int j2 = 0; j2 < 16; j2++) A[j2] = Zh[base + (j2 ^ k2t)];
        #pragma unroll
        for (int j2 = 0; j2 < 16; j2++) B[j2] = Zh[base + (j2 ^ k2t) + 16];
        if (f == 0) {
            #pragma unroll
            for (int j2 = 0; j2 < 16; j2++) y[j2] = cadd(A[j2], B[j2]);
        } else {
            #pragma unroll
            for (int j2 = 0; j2 < 16; j2++)
                y[j2] = cmul(csub(A[j2], B[j2]), make_float2(TW32R[j2], TW32I[j2]));
        }
        __syncthreads();                          // all L2 reads done before spectrum store
        fft16(y);
        #pragma unroll
        for (int p = 0; p < 16; p++) {
            int s2 = BR4[p];
            int k = k1t + (k2t << 4) + (f << 8) + (s2 << 9);
            Zh[(k & ~31) | ((k & 31) ^ ((k >> 5) & 31))] = y[p];  // natural k, swizzled low5
        }
        __syncthreads();                          // both spectra ready
    }

    // -------- rfft unpack of both spectra + pointwise products, 8 bins/thread --------
    float2* ZS = Z;
    float2* ZH = Z + 8192;
    float2 zs0 = ZS[0], zh0 = ZH[0];
    const float s_nyq = zs0.x - zs0.y;
    const float h_nyq = zh0.x - zh0.y;

    float hh[8], hs[8];                          // |H|^2, Re(conj(H)*S)
    {
        float2 cv = twC[t];                      // W_2048^t = W_16384^{8t}
        #pragma unroll
        for (int i = 0; i < 8; i++) {
            int k = (t << 3) + i;
            int m = (8192 - k) & 8191;
            int ak = (k & ~31) | ((k & 31) ^ ((k >> 5) & 31));
            int am = (m & ~31) | ((m & 31) ^ ((m >> 5) & 31));
            float2 As = ZS[ak], Bs = ZS[am];
            float2 Ah = ZH[ak], Bh = ZH[am];
            float2 w = cmul(cv, twI[i]);         // W_16384^k
            float Er = 0.5f*(As.x + Bs.x), Ei = 0.5f*(As.y - Bs.y);
            float Dr = 0.5f*(As.x - Bs.x), Di = 0.5f*(As.y + Bs.y);
            float sr = Er + w.x*Di + w.y*Dr;
            float si = Ei + w.y*Di - w.x*Dr;
            Er = 0.5f*(Ah.x + Bh.x); Ei = 0.5f*(Ah.y - Bh.y);
            Dr = 0.5f*(Ah.x - Bh.x); Di = 0.5f*(Ah.y + Bh.y);
            float hr = Er + w.x*Di + w.y*Dr;
            float hi = Ei + w.y*Di - w.x*Dr;
            hh[i] = hr*hr + hi*hi;
            hs[i] = hr*sr + hi*si;
        }
    }
    __syncthreads();                             // all spectrum reads done; LDS free

    // -------- cum_h: wave shuffle scan over 16 waves --------
    const int SCANW = 16500;                     // 16 floats (upper half dead)
    const int EDG   = 16520;                     // 17 ints
    const int BINS  = 16544;                     // 16 floats
    const int TOT   = 16561;

    float run = 0.f;
    #pragma unroll
    for (int i = 0; i < 8; i++) run += ALPHA * hh[i];

    const int lane = t & 63, wid = t >> 6;
    float v = run;
    #pragma unroll
    for (int off = 1; off < 64; off <<= 1) {
        float o = __shfl_up(v, off, 64);
        if (lane >= off) v += o;
    }
    if (lane == 63) F[SCANW + wid] = v;
    __syncthreads();
    float wbase = 0.f;
    #pragma unroll
    for (int w2 = 0; w2 < 15; w2++) if (w2 < wid) wbase += F[SCANW + w2];
    float base = wbase + v - run;                // exclusive prefix

    float cum = base;
    #pragma unroll
    for (int i = 0; i < 8; i++) {                // cum at phys(k)=k+(k>>5)
        cum += ALPHA * hh[i];
        int k = (t << 3) + i;
        F[k + (k >> 5)] = cum;
    }
    if (t == 1023) F[8448] = cum + ALPHA * h_nyq * h_nyq;   // cum_h[8192]
    __syncthreads();

    // -------- edges (searchsorted right) + bin init --------
    float total_h = F[8448];
    if (t < 17) {
        float target = (float)t * 0.0625f * total_h;
        int lo = 0, hi = 8193;
        while (lo < hi) {
            int mid = (lo + hi) >> 1;
            float vv = F[mid + (mid >> 5)];
            if (vv <= target) lo = mid + 1; else hi = mid;
        }
        I[EDG + t] = lo < 8192 ? lo : 8192;
    }
    if (t >= 64 && t < 80) F[BINS + (t - 64)] = 0.f;
    if (t == 80) F[TOT] = 0.f;
    __syncthreads();

    int e[17];
    #pragma unroll
    for (int i = 0; i < 17; i++) e[i] = I[EDG + i];

    float invs = 1.0f / sqrtf(total_h);
    float qs   = ALPHA * invs;

    // -------- segmented bin sums + total --------
    float tot = 0.f, acc = 0.f;
    int   cur = -1;
    #pragma unroll
    for (int i = 0; i < 8; i++) {
        int   k = (t << 3) + i;
        float r = qs * hs[i];
        tot += r;
        int bn = -1;                             // k in bin bn iff e[bn] < k <= e[bn+1]
        #pragma unroll
        for (int j = 0; j < 17; j++) bn += (e[j] < k) ? 1 : 0;
        if (bn != cur) {
            if (cur >= 0) atomicAdd(&F[BINS + cur], acc);
            acc = 0.f;
            cur = bn;
        }
        acc += r;
    }
    if (cur >= 0) atomicAdd(&F[BINS + cur], acc);

    #pragma unroll
    for (int off = 32; off > 0; off >>= 1) tot += __shfl_down(tot, off);
    if ((t & 63) == 0) atomicAdd(&F[TOT], tot);

    if (t == 0) {                                // Nyquist term (k = 8192)
        float rn = qs * (h_nyq * s_nyq);
        atomicAdd(&F[TOT], rn);
        int bn = -1;
        #pragma unroll
        for (int j = 0; j < 17; j++) bn += (e[j] < 8192) ? 1 : 0;
        if (bn >= 0) atomicAdd(&F[BINS + bn], rn);
    }
    __syncthreads();

    if (t == 0) {
        float total = F[TOT];
        float mean  = total * 0.0625f;
        float chisq = 0.f;
        #pragma unroll
        for (int j = 0; j < 16; j++) {
            float d = F[BINS + j] - mean;
            chisq += d * d;
        }
        out[row] = chisq * (16.0f / 15.0f);
    }
}

extern "C" void kernel_launch(void* const* d_in, const int* in_sizes, int n_in,
                              void* d_out, int out_size, void* d_ws, size_t ws_size,
                              hipStream_t stream) {
    const float* tmpl = (const float*)d_in[0];
    const float* strn = (const float*)d_in[1];
    float* outp = (float*)d_out;
    float2* ws  = (float2*)d_ws;                 // ~12.3 KiB twiddle tables

    int rows = in_sizes[0] / 16384;              // 1024

    hipLaunchKernelGGL(init_tw, dim3(2), dim3(1024), 0, stream, ws);
    hipLaunchKernelGGL(chisq_kernel, dim3(rows), dim3(1024), 0, stream,
                       tmpl, strn, ws, outp);
}

// Round 5
// 81.794 us; speedup vs baseline: 6.1127x; 1.0094x over previous
//
#include <hip/hip_runtime.h>
#include <math.h>

#define DPI 3.14159265358979323846

__device__ __forceinline__ float2 cmul(float2 a, float2 b) {
    return make_float2(a.x*b.x - a.y*b.y, a.x*b.y + a.y*b.x);
}
__device__ __forceinline__ float2 cadd(float2 a, float2 b){ return make_float2(a.x+b.x, a.y+b.y); }
__device__ __forceinline__ float2 csub(float2 a, float2 b){ return make_float2(a.x-b.x, a.y-b.y); }

// W_32^m = (cos, -sin)(2*pi*m/32), m = 0..15
__device__ const float TW32R[16] = {
    1.0f, 0.98078528040323045f, 0.92387953251128676f, 0.83146961230254524f,
    0.70710678118654752f, 0.55557023301960222f, 0.38268343236508977f, 0.19509032201612827f,
    0.0f, -0.19509032201612827f, -0.38268343236508977f, -0.55557023301960222f,
    -0.70710678118654752f, -0.83146961230254524f, -0.92387953251128676f, -0.98078528040323045f };
__device__ const float TW32I[16] = {
    0.0f, -0.19509032201612827f, -0.38268343236508977f, -0.55557023301960222f,
    -0.70710678118654752f, -0.83146961230254524f, -0.92387953251128676f, -0.98078528040323045f,
    -1.0f, -0.98078528040323045f, -0.92387953251128676f, -0.83146961230254524f,
    -0.70710678118654752f, -0.55557023301960222f, -0.38268343236508977f, -0.19509032201612827f };

__device__ const int BR4[16] = {0,8,4,12,2,10,6,14,1,9,5,13,3,11,7,15};

// DIF stage for register FFT of size 16, butterfly half-span H.
template<int H>
__device__ __forceinline__ void stage16(float2* y) {
    #pragma unroll
    for (int g = 0; g < 16; g += 2*H) {
        #pragma unroll
        for (int j = 0; j < H; j++) {
            float2 u = y[g+j], v = y[g+j+H];
            y[g+j] = cadd(u, v);
            float2 d = csub(u, v);
            const int m = j * (16 / H);
            y[g+j+H] = (j == 0) ? d : cmul(d, make_float2(TW32R[m], TW32I[m]));
        }
    }
}
__device__ __forceinline__ void fft16(float2* y) {
    stage16<8>(y); stage16<4>(y); stage16<2>(y); stage16<1>(y);
}   // y[p] = OUT[BR4[p]]

// wp[m] = w^m, m=0..15, mult depth <= 3
__device__ __forceinline__ void pow16(float2 w, float2* wp) {
    wp[0] = make_float2(1.f, 0.f);
    wp[1] = w;
    wp[2] = cmul(w, w);
    wp[3] = cmul(wp[2], w);
    wp[4] = cmul(wp[2], wp[2]);
    wp[5] = cmul(wp[4], wp[1]);
    wp[6] = cmul(wp[4], wp[2]);
    wp[7] = cmul(wp[4], wp[3]);
    wp[8] = cmul(wp[4], wp[4]);
    wp[9] = cmul(wp[8], wp[1]);
    wp[10] = cmul(wp[8], wp[2]);
    wp[11] = cmul(wp[8], wp[3]);
    wp[12] = cmul(wp[8], wp[4]);
    wp[13] = cmul(wp[8], wp[5]);
    wp[14] = cmul(wp[8], wp[6]);
    wp[15] = cmul(wp[8], wp[7]);
}

// ws layout (float2): [0,512) W_8192^u | [512,544) W_512^j | [544,1568) W_2048^t | [1568,1576) W_16384^i
static __global__ void init_tw(float2* __restrict__ ws) {
    int g = blockIdx.x * 1024 + threadIdx.x;
    if (g < 512) {
        ws[g] = make_float2((float)cos(DPI*g/4096.0), (float)(-sin(DPI*g/4096.0)));
    } else if (g < 544) {
        int j = g - 512;
        ws[g] = make_float2((float)cos(DPI*j/256.0), (float)(-sin(DPI*j/256.0)));
    } else if (g < 1568) {
        int q = g - 544;
        ws[g] = make_float2((float)cos(DPI*q/1024.0), (float)(-sin(DPI*q/1024.0)));
    } else if (g < 1576) {
        int i = g - 1568;
        ws[g] = make_float2((float)cos(DPI*i/8192.0), (float)(-sin(DPI*i/8192.0)));
    }
}

__launch_bounds__(1024, 4)   // 4 waves/EU = exactly the LDS-capped occupancy -> 128 VGPR budget
static __global__ void chisq_kernel(const float* __restrict__ tmpl,
                                    const float* __restrict__ strn,
                                    const float2* __restrict__ ws,
                                    float* __restrict__ out)
{
    __shared__ float2 Z[16384];                 // 128 KiB: [0,8192)=strain, [8192,16384)=template
    float* F = reinterpret_cast<float*>(Z);
    int*   I = reinterpret_cast<int*>(Z);

    const int t    = threadIdx.x;               // 0..1023
    const int half = t >> 9;                    // 0 = strain, 1 = template
    const int u    = t & 511;
    const int row  = blockIdx.x;
    const float ALPHA = 1.1920928955078125e-7f; // 4*DF/fs^2 = 2^-23

    const float2* tw8192 = ws;                  // W_8192^u, u<512
    const float2* tw512  = ws + 512;            // W_512^j,  j<32
    const float2* twC    = ws + 544;            // W_2048^t, t<1024
    const float2* twI    = ws + 1568;           // W_16384^i, i<8

    float2* Zh = Z + (half << 13);
    const float* src = (half ? tmpl : strn) + (size_t)row * 16384;

    // -------- FFT 8192 = 16 x 16 x (2 x 16), 512 threads/signal, 16 elems/thread --------
    {
        const float2* x = reinterpret_cast<const float2*>(src);
        float2 y[16];

        // ---- stage 1: fft16 over n1 (n = n1*512 + u), twiddle W_8192^{u*k1} ----
        #pragma unroll
        for (int n1 = 0; n1 < 16; n1++) y[n1] = x[n1*512 + u];
        fft16(y);
        {
            float2 wp[16]; pow16(tw8192[u], wp);
            #pragma unroll
            for (int p = 0; p < 16; p++) {
                int k1 = BR4[p];
                float2 val = y[p];
                if (k1 > 0) val = cmul(val, wp[k1]);
                Zh[(u << 4) | (k1 ^ (u & 15))] = val;   // L1[u][k1], swizzled
            }
        }
        __syncthreads();

        // ---- stage 2: fft16 over n2 (u = n2*32 + j), twiddle W_512^{j*k2} ----
        const int k1s = u >> 5, js = u & 31;
        #pragma unroll
        for (int n2 = 0; n2 < 16; n2++)
            y[n2] = Zh[((n2*32 + js) << 4) | (k1s ^ (js & 15))];
        __syncthreads();                          // all L1 reads done before L2 writes
        fft16(y);
        {
            float2 wq[16]; pow16(tw512[js], wq);
            #pragma unroll
            for (int p = 0; p < 16; p++) {
                int k2 = BR4[p];
                float2 val = y[p];
                if (k2 > 0) val = cmul(val, wq[k2]);
                Zh[(k1s << 9) + (k2 << 5) + (js ^ k2)] = val;  // L2[k1][k2][j], swizzled
            }
        }
        __syncthreads();

        // ---- stage 3: radix-2 (j2, j2+16) fused into the load + fft16 over j2 ----
        // f=0: sum-half; f=1: diff-half * W_32^{j2}. f is wave-uniform.
        const int f = u >> 8, k1t = (u >> 4) & 15, k2t = u & 15;
        const int base = (k1t << 9) + (k2t << 5);
        if (f == 0) {
            #pragma unroll
            for (int j2 = 0; j2 < 16; j2++) {
                float2 a = Zh[base + (j2 ^ k2t)];
                float2 b = Zh[base + (j2 ^ k2t) + 16];
                y[j2] = cadd(a, b);
            }
        } else {
            #pragma unroll
            for (int j2 = 0; j2 < 16; j2++) {
                float2 a = Zh[base + (j2 ^ k2t)];
                float2 b = Zh[base + (j2 ^ k2t) + 16];
                y[j2] = cmul(csub(a, b), make_float2(TW32R[j2], TW32I[j2]));
            }
        }
        __syncthreads();                          // all L2 reads done before spectrum store
        fft16(y);
        #pragma unroll
        for (int p = 0; p < 16; p++) {
            int s2 = BR4[p];
            int k = k1t + (k2t << 4) + (f << 8) + (s2 << 9);
            Zh[(k & ~31) | ((k & 31) ^ ((k >> 5) & 31))] = y[p];  // natural k, swizzled low5
        }
        __syncthreads();                          // both spectra ready
    }

    // -------- rfft unpack of both spectra + pointwise products, 8 bins/thread --------
    float2* ZS = Z;
    float2* ZH = Z + 8192;
    float2 zs0 = ZS[0], zh0 = ZH[0];
    const float s_nyq = zs0.x - zs0.y;
    const float h_nyq = zh0.x - zh0.y;

    float hh[8], hs[8];                          // |H|^2, Re(conj(H)*S)
    {
        float2 cv = twC[t];                      // W_2048^t = W_16384^{8t}
        #pragma unroll
        for (int i = 0; i < 8; i++) {
            int k = (t << 3) + i;
            int m = (8192 - k) & 8191;
            int ak = (k & ~31) | ((k & 31) ^ ((k >> 5) & 31));
            int am = (m & ~31) | ((m & 31) ^ ((m >> 5) & 31));
            float2 As = ZS[ak], Bs = ZS[am];
            float2 Ah = ZH[ak], Bh = ZH[am];
            float2 w = cmul(cv, twI[i]);         // W_16384^k
            float Er = 0.5f*(As.x + Bs.x), Ei = 0.5f*(As.y - Bs.y);
            float Dr = 0.5f*(As.x - Bs.x), Di = 0.5f*(As.y + Bs.y);
            float sr = Er + w.x*Di + w.y*Dr;
            float si = Ei + w.y*Di - w.x*Dr;
            Er = 0.5f*(Ah.x + Bh.x); Ei = 0.5f*(Ah.y - Bh.y);
            Dr = 0.5f*(Ah.x - Bh.x); Di = 0.5f*(Ah.y + Bh.y);
            float hr = Er + w.x*Di + w.y*Dr;
            float hi = Ei + w.y*Di - w.x*Dr;
            hh[i] = hr*hr + hi*hi;
            hs[i] = hr*sr + hi*si;
        }
    }
    __syncthreads();                             // all spectrum reads done; LDS free

    // -------- cum_h: wave shuffle scan over 16 waves --------
    const int SCANW = 16500;                     // 16 floats (upper half dead)
    const int EDG   = 16520;                     // 17 ints
    const int BINS  = 16544;                     // 16 floats
    const int TOT   = 16561;

    float run = 0.f;
    #pragma unroll
    for (int i = 0; i < 8; i++) run += ALPHA * hh[i];

    const int lane = t & 63, wid = t >> 6;
    float v = run;
    #pragma unroll
    for (int off = 1; off < 64; off <<= 1) {
        float o = __shfl_up(v, off, 64);
        if (lane >= off) v += o;
    }
    if (lane == 63) F[SCANW + wid] = v;
    __syncthreads();
    float wbase = 0.f;
    #pragma unroll
    for (int w2 = 0; w2 < 15; w2++) if (w2 < wid) wbase += F[SCANW + w2];
    float base = wbase + v - run;                // exclusive prefix

    float cum = base;
    #pragma unroll
    for (int i = 0; i < 8; i++) {                // cum at phys(k)=k+(k>>5)
        cum += ALPHA * hh[i];
        int k = (t << 3) + i;
        F[k + (k >> 5)] = cum;
    }
    if (t == 1023) F[8448] = cum + ALPHA * h_nyq * h_nyq;   // cum_h[8192]
    __syncthreads();

    // -------- edges (searchsorted right) + bin init --------
    float total_h = F[8448];
    if (t < 17) {
        float target = (float)t * 0.0625f * total_h;
        int lo = 0, hi = 8193;
        while (lo < hi) {
            int mid = (lo + hi) >> 1;
            float vv = F[mid + (mid >> 5)];
            if (vv <= target) lo = mid + 1; else hi = mid;
        }
        I[EDG + t] = lo < 8192 ? lo : 8192;
    }
    if (t >= 64 && t < 80) F[BINS + (t - 64)] = 0.f;
    if (t == 80) F[TOT] = 0.f;
    __syncthreads();

    int e[17];
    #pragma unroll
    for (int i = 0; i < 17; i++) e[i] = I[EDG + i];

    float invs = 1.0f / sqrtf(total_h);
    float qs   = ALPHA * invs;

    // -------- segmented bin sums + total --------
    float tot = 0.f, acc = 0.f;
    int   cur = -1;
    #pragma unroll
    for (int i = 0; i < 8; i++) {
        int   k = (t << 3) + i;
        float r = qs * hs[i];
        tot += r;
        int bn = -1;                             // k in bin bn iff e[bn] < k <= e[bn+1]
        #pragma unroll
        for (int j = 0; j < 17; j++) bn += (e[j] < k) ? 1 : 0;
        if (bn != cur) {
            if (cur >= 0) atomicAdd(&F[BINS + cur], acc);
            acc = 0.f;
            cur = bn;
        }
        acc += r;
    }
    if (cur >= 0) atomicAdd(&F[BINS + cur], acc);

    #pragma unroll
    for (int off = 32; off > 0; off >>= 1) tot += __shfl_down(tot, off);
    if ((t & 63) == 0) atomicAdd(&F[TOT], tot);

    if (t == 0) {                                // Nyquist term (k = 8192)
        float rn = qs * (h_nyq * s_nyq);
        atomicAdd(&F[TOT], rn);
        int bn = -1;
        #pragma unroll
        for (int j = 0; j < 17; j++) bn += (e[j] < 8192) ? 1 : 0;
        if (bn >= 0) atomicAdd(&F[BINS + bn], rn);
    }
    __syncthreads();

    if (t == 0) {
        float total = F[TOT];
        float mean  = total * 0.0625f;
        float chisq = 0.f;
        #pragma unroll
        for (int j = 0; j < 16; j++) {
            float d = F[BINS + j] - mean;
            chisq += d * d;
        }
        out[row] = chisq * (16.0f / 15.0f);
    }
}

extern "C" void kernel_launch(void* const* d_in, const int* in_sizes, int n_in,
                              void* d_out, int out_size, void* d_ws, size_t ws_size,
                              hipStream_t stream) {
    const float* tmpl = (const float*)d_in[0];
    const float* strn = (const float*)d_in[1];
    float* outp = (float*)d_out;
    float2* ws  = (float2*)d_ws;                 // ~12.3 KiB twiddle tables

    int rows = in_sizes[0] / 16384;              // 1024

    hipLaunchKernelGGL(init_tw, dim3(2), dim3(1024), 0, stream, ws);
    hipLaunchKernelGGL(chisq_kernel, dim3(rows), dim3(1024), 0, stream,
                       tmpl, strn, ws, outp);
}